// Round 5
// baseline (244.928 us; speedup 1.0000x reference)
//
#include <hip/hip_runtime.h>
#include <math.h>

#define NLOC 1600          // 40*40 local nodes
#define NGLO 100           // 10*10 global nodes

typedef unsigned short u16;
typedef short s16x8 __attribute__((ext_vector_type(8)));   // 8 bf16 (4 VGPRs)
typedef float f32x4 __attribute__((ext_vector_type(4)));   // MFMA C/D

__device__ __forceinline__ short f2bf(float f) {           // RNE f32->bf16
    unsigned u = __float_as_uint(f);
    u += 0x7fffu + ((u >> 16) & 1u);
    return (short)(u >> 16);
}
__device__ __forceinline__ float bf2f(u16 h) {
    return __uint_as_float(((unsigned)h) << 16);
}

// ===========================================================================
// Device helpers
// ===========================================================================

// Plain MFMA GEMM tile: C[m0..m0+32][n0..n0+64] = A[M,256] @ W^T + bias, bf16 out.
__device__ __forceinline__ void gemm_tile(int lane, const u16* __restrict__ A,
                                          const u16* __restrict__ W,
                                          const float* __restrict__ bias,
                                          u16* __restrict__ C, int M, int m0, int n0) {
    int c = lane & 15, qd = lane >> 4;
    f32x4 acc[2][4] = {};
#pragma unroll 2
    for (int kc = 0; kc < 8; ++kc) {
        int ko = kc * 32 + qd * 8;
        s16x8 af[2], bf[4];
#pragma unroll
        for (int mi = 0; mi < 2; ++mi) {
            int row = m0 + mi * 16 + c;
            s16x8 zz = {};
            af[mi] = (row < M) ? *(const s16x8*)(A + (size_t)row * 256 + ko) : zz;
        }
#pragma unroll
        for (int ni = 0; ni < 4; ++ni)
            bf[ni] = *(const s16x8*)(W + (size_t)(n0 + ni * 16 + c) * 256 + ko);
#pragma unroll
        for (int mi = 0; mi < 2; ++mi)
#pragma unroll
            for (int ni = 0; ni < 4; ++ni)
                acc[mi][ni] = __builtin_amdgcn_mfma_f32_16x16x32_bf16(af[mi], bf[ni],
                                                                      acc[mi][ni], 0, 0, 0);
    }
#pragma unroll
    for (int mi = 0; mi < 2; ++mi)
#pragma unroll
        for (int r = 0; r < 4; ++r) {
            int row = m0 + mi * 16 + 4 * qd + r;
            if (row < M) {
#pragma unroll
                for (int ni = 0; ni < 4; ++ni) {
                    int col = n0 + ni * 16 + c;
                    C[(size_t)row * 256 + col] = (u16)f2bf(acc[mi][ni][r] + bias[col]);
                }
            }
        }
}

// Fused GEMM + LayerNorm: 16 rows x all 256 cols per wave.
// y = LN(A@W^T + bias + R) * g + bb.
// mode 0: fout[row][col] f32 + bfout bf16 shadow.
// mode 1: dout[(b*256+col)*1600 + row/2] (final BCHW write), row = n*2+b.
__device__ __forceinline__ void gemmln_wave(int lane, const u16* __restrict__ A,
                                            const u16* __restrict__ W,
                                            const float* __restrict__ bias,
                                            const float* __restrict__ R,
                                            const float* __restrict__ g,
                                            const float* __restrict__ bb,
                                            float* fout, u16* bfout, float* dout,
                                            int M, int m0, int mode) {
    int c = lane & 15, qd = lane >> 4;
    f32x4 acc[16] = {};
#pragma unroll 2
    for (int kc = 0; kc < 8; ++kc) {
        int ko = kc * 32 + qd * 8;
        int row = m0 + c;
        s16x8 zz = {};
        s16x8 af = (row < M) ? *(const s16x8*)(A + (size_t)row * 256 + ko) : zz;
#pragma unroll
        for (int ni = 0; ni < 16; ++ni) {
            s16x8 bf = *(const s16x8*)(W + (size_t)(ni * 16 + c) * 256 + ko);
            acc[ni] = __builtin_amdgcn_mfma_f32_16x16x32_bf16(af, bf, acc[ni], 0, 0, 0);
        }
    }
#pragma unroll
    for (int r = 0; r < 4; ++r) {
        int row = m0 + 4 * qd + r;            // uniform across the 16-lane c-group
        bool ok = (row < M);
        float v[16];
        float s1 = 0.f, s2 = 0.f;
#pragma unroll
        for (int ni = 0; ni < 16; ++ni) {
            int col = ni * 16 + c;
            float val = acc[ni][r] + bias[col] + (ok ? R[(size_t)row * 256 + col] : 0.f);
            v[ni] = val;
            s1 += val; s2 += val * val;
        }
        s1 += __shfl_xor(s1, 1); s2 += __shfl_xor(s2, 1);
        s1 += __shfl_xor(s1, 2); s2 += __shfl_xor(s2, 2);
        s1 += __shfl_xor(s1, 4); s2 += __shfl_xor(s2, 4);
        s1 += __shfl_xor(s1, 8); s2 += __shfl_xor(s2, 8);
        float mean = s1 * (1.f / 256.f);
        float var  = s2 * (1.f / 256.f) - mean * mean;
        float rstd = rsqrtf(var + 1e-5f);
        if (ok) {
            if (mode == 0) {
#pragma unroll
                for (int ni = 0; ni < 16; ++ni) {
                    int col = ni * 16 + c;
                    float y = (v[ni] - mean) * rstd * g[col] + bb[col];
                    fout[(size_t)row * 256 + col] = y;
                    bfout[(size_t)row * 256 + col] = (u16)f2bf(y);
                }
            } else {
                int n = row >> 1, b = row & 1;
#pragma unroll
                for (int ni = 0; ni < 16; ++ni) {
                    int col = ni * 16 + c;
                    float y = (v[ni] - mean) * rstd * g[col] + bb[col];
                    dout[((size_t)(b * 256 + col)) * 1600 + n] = y;
                }
            }
        }
    }
}

// ===========================================================================
// K1: wconv (768 blocks) + prep transpose/pool (3400 blocks)
// ===========================================================================
__global__ __launch_bounds__(256) void k_prep(const float* __restrict__ gw,
                                              const float* __restrict__ cw,
                                              u16* __restrict__ gwb,
                                              u16* __restrict__ cwb,
                                              const float* __restrict__ x,
                                              float* __restrict__ nodes,
                                              u16* __restrict__ nodesb,
                                              float* __restrict__ gn,
                                              u16* __restrict__ gnb) {
    int bx = blockIdx.x;
    if (bx < 768) {
        int t = bx * 256 + threadIdx.x;    // 0..196607
        const float* src; u16* dst; int idx;
        if (t < 131072) { src = gw; dst = gwb; idx = t; }
        else            { src = cw; dst = cwb; idx = t - 131072; }
        float4 v = ((const float4*)src)[idx];
        ushort4 o;
        o.x = (u16)f2bf(v.x); o.y = (u16)f2bf(v.y);
        o.z = (u16)f2bf(v.z); o.w = (u16)f2bf(v.w);
        ((ushort4*)dst)[idx] = o;
        return;
    }
    int bid = bx - 768;
    if (bid < 3200) {
        int t = bid * 256 + threadIdx.x;
        int c = t & 255;
        int b = (t >> 8) & 1;
        int n = t >> 9;
        float v = x[((size_t)(b * 256 + c)) * 1600 + n];
        nodes[t] = v;
        nodesb[t] = (u16)f2bf(v);
    } else {
        int t = (bid - 3200) * 256 + threadIdx.x;
        int c = t & 255;
        int b = (t >> 8) & 1;
        int n = t >> 9;
        int p = n / 10, qq = n - p * 10;
        const float* xp = x + ((size_t)(b * 256 + c)) * 1600 + (p * 4) * 40 + qq * 4;
        float s = 0.f;
#pragma unroll
        for (int dy = 0; dy < 4; ++dy)
#pragma unroll
            for (int dx = 0; dx < 4; ++dx)
                s += xp[dy * 40 + dx];
        s *= (1.f / 16.f);
        gn[t] = s;
        gnb[t] = (u16)f2bf(s);
    }
}

// ===========================================================================
// K2: QKV GEMMs, local (bx<100) + global (bx>=100). grid (107, 4, 3), 64 thr.
// Also zero-inits sv1l/sv1g (512 contiguous floats) from block (100,0,0).
// ===========================================================================
__global__ __launch_bounds__(64) void k_qkv(const u16* __restrict__ nodesb,
                                            const u16* __restrict__ gnb,
                                            const u16* __restrict__ W1b,
                                            const u16* __restrict__ W0b,
                                            const float* __restrict__ b1,
                                            const float* __restrict__ b0,
                                            u16* __restrict__ qbuf,
                                            u16* __restrict__ gqb,
                                            float* __restrict__ sv1) {
    int lane = threadIdx.x;
    int bx = blockIdx.x, z = blockIdx.z;
    int n0 = blockIdx.y * 64;
    if (bx == 100 && blockIdx.y == 0 && z == 0) {
#pragma unroll
        for (int i = 0; i < 8; ++i) sv1[lane * 8 + i] = 0.f;
    }
    if (bx < 100)
        gemm_tile(lane, nodesb, W1b + (size_t)z * 65536, b1 + z * 256,
                  qbuf + (size_t)z * 819200, 3200, bx * 32, n0);
    else
        gemm_tile(lane, gnb, W0b + (size_t)z * 65536, b0 + z * 256,
                  gqb + (size_t)z * 51200, 200, (bx - 100) * 32, n0);
}

// ===========================================================================
// K3: V transpose + fused colsum (batch-1) atomics.
// grid (108, 8): bx<100 local (vbuf->vtb, M=3200, Npad=1600, sv1l),
//                bx>=100 global (gvb->gvt, M=200, Npad=128, sv1g).
// ===========================================================================
__device__ __forceinline__ void vtrans_block(const u16* __restrict__ src,
                                             u16* __restrict__ dst,
                                             int M, int Npad, int bxx, int byy,
                                             float* sum) {
    __shared__ u16 tile[32][33];
    int m0 = bxx * 32;
    int e0 = byy * 32;
    int tx = threadIdx.x & 31, ty = threadIdx.x >> 5;
#pragma unroll
    for (int k2 = 0; k2 < 4; ++k2) {
        int m = m0 + ty + k2 * 8;
        tile[ty + k2 * 8][tx] = (m < M) ? src[(size_t)m * 256 + e0 + tx] : (u16)0;
    }
    __syncthreads();
    int b = tx >> 4, nl = tx & 15;
    int n = (m0 >> 1) + nl;
    if (n < Npad) {
#pragma unroll
        for (int k2 = 0; k2 < 4; ++k2) {
            int e = e0 + ty + k2 * 8;
            dst[(size_t)(b * 256 + e) * Npad + n] = tile[2 * nl + b][ty + k2 * 8];
        }
    }
    if (threadIdx.x < 32) {
        float s = 0.f;
#pragma unroll
        for (int r = 0; r < 16; ++r) s += bf2f(tile[2 * r + 1][threadIdx.x]);
        atomicAdd(&sum[e0 + threadIdx.x], s);
    }
}

__global__ __launch_bounds__(256) void k_vtrans(const u16* __restrict__ vbuf,
                                                u16* __restrict__ vtb,
                                                const u16* __restrict__ gvb,
                                                u16* __restrict__ gvt,
                                                float* __restrict__ sv1l,
                                                float* __restrict__ sv1g) {
    int bx = blockIdx.x;
    if (bx < 100) vtrans_block(vbuf, vtb, 3200, 1600, bx, blockIdx.y, sv1l);
    else          vtrans_block(gvb, gvt, 200, 128, bx - 100, blockIdx.y, sv1g);
}

// ===========================================================================
// K4: attention. blocks 0..799: local GAT (4-wave, LDS-staged, j-quarters);
// blocks 800..813: global GAT (wave-per-(h,it), 56 wave tasks).
// a0 = sigmoid((q1k1-q0k0)/sqrt32); edge bias cancels; O1 = sumV1 - sum a0*V1.
// ===========================================================================
__global__ __launch_bounds__(256) void k_attn(
    const u16* __restrict__ qb, const u16* __restrict__ kb,
    const u16* __restrict__ vt, float* __restrict__ pO, float* __restrict__ pT,
    const u16* __restrict__ gqb, const u16* __restrict__ gkb,
    const u16* __restrict__ gvt, const float* __restrict__ sv1g,
    u16* __restrict__ gattb)
{
    __shared__ u16 ks[2][32][40];
    __shared__ u16 vs[2][32][40];
    __shared__ short At4[4][16][40];

    int tid = threadIdx.x;
    int w = tid >> 6, lane = tid & 63;
    int c = lane & 15, qd = lane >> 4;
    int bx = blockIdx.x;

    if (bx < 800) {
        // ---------------- local ----------------
        int q4 = bx & 3;
        int hic = bx >> 2;
        int ic = hic % 25, h = hic / 25;
        int hb = h * 32;
        int i0 = ic * 64 + w * 16;
        int jb0 = q4 * 13, jbe = (jb0 + 13 < 50) ? jb0 + 13 : 50;

        const u16* qp = qb + ((size_t)(i0 + c) * 2) * 256 + hb + qd * 8;
        s16x8 qf0 = *(const s16x8*)qp;
        s16x8 qf1 = *(const s16x8*)(qp + 256);
#pragma unroll
        for (int z = 0; z < 8; ++z) qf0[z] ^= (short)0x8000;

        f32x4 o0[2] = {}, t1[2] = {};

        int srow = tid >> 2, part = tid & 3;
        int sjl = srow >> 1, sb = srow & 1;
        int vb_ = srow >> 5, vd = srow & 31;

        for (int jb = jb0; jb < jbe; ++jb) {
            int j0 = jb * 32;
            __syncthreads();
            {
                s16x8 kv = *(const s16x8*)(kb + (size_t)(j0 + sjl) * 512 + sb * 256 + hb + part * 8);
                *(s16x8*)&ks[sb][sjl][part * 8] = kv;
                s16x8 vv = *(const s16x8*)(vt + (size_t)(vb_ * 256 + hb + vd) * 1600 + j0 + part * 8);
                *(s16x8*)&vs[vb_][vd][part * 8] = vv;
            }
            __syncthreads();

            s16x8 kf00 = *(const s16x8*)&ks[0][c][qd * 8];
            s16x8 kf10 = *(const s16x8*)&ks[1][c][qd * 8];
            s16x8 kf01 = *(const s16x8*)&ks[0][16 + c][qd * 8];
            s16x8 kf11 = *(const s16x8*)&ks[1][16 + c][qd * 8];

            f32x4 z4 = {};
            f32x4 sd0 = __builtin_amdgcn_mfma_f32_16x16x32_bf16(qf0, kf00, z4, 0, 0, 0);
            sd0       = __builtin_amdgcn_mfma_f32_16x16x32_bf16(qf1, kf10, sd0, 0, 0, 0);
            f32x4 sd1 = __builtin_amdgcn_mfma_f32_16x16x32_bf16(qf0, kf01, z4, 0, 0, 0);
            sd1       = __builtin_amdgcn_mfma_f32_16x16x32_bf16(qf1, kf11, sd1, 0, 0, 0);
#pragma unroll
            for (int r = 0; r < 4; ++r) {
                float e0v = __expf(sd0[r] * 0.17677669529663687f);
                At4[w][4 * qd + r][c]      = f2bf(__builtin_amdgcn_rcpf(1.f + e0v));
                float e1v = __expf(sd1[r] * 0.17677669529663687f);
                At4[w][4 * qd + r][16 + c] = f2bf(__builtin_amdgcn_rcpf(1.f + e1v));
            }
            asm volatile("s_waitcnt lgkmcnt(0)" ::: "memory");
            s16x8 af = *(const s16x8*)&At4[w][c][qd * 8];

            s16x8 vf00 = *(const s16x8*)&vs[0][c][qd * 8];
            s16x8 vf01 = *(const s16x8*)&vs[0][16 + c][qd * 8];
            s16x8 vf10 = *(const s16x8*)&vs[1][c][qd * 8];
            s16x8 vf11 = *(const s16x8*)&vs[1][16 + c][qd * 8];

            o0[0] = __builtin_amdgcn_mfma_f32_16x16x32_bf16(af, vf00, o0[0], 0, 0, 0);
            o0[1] = __builtin_amdgcn_mfma_f32_16x16x32_bf16(af, vf01, o0[1], 0, 0, 0);
            t1[0] = __builtin_amdgcn_mfma_f32_16x16x32_bf16(af, vf10, t1[0], 0, 0, 0);
            t1[1] = __builtin_amdgcn_mfma_f32_16x16x32_bf16(af, vf11, t1[1], 0, 0, 0);
        }

        size_t base = (size_t)q4 * 409600;
#pragma unroll
        for (int dh = 0; dh < 2; ++dh)
#pragma unroll
            for (int r = 0; r < 4; ++r) {
                size_t idx = base + (size_t)(i0 + 4 * qd + r) * 256 + hb + dh * 16 + c;
                pO[idx] = o0[dh][r];
                pT[idx] = t1[dh][r];
            }
    } else {
        // ---------------- global (N=100, Npad=128) ----------------
        int idx = (bx - 800) * 4 + w;      // 0..55 exact
        int h = idx / 7, it = idx % 7;
        int i0 = it * 16;
        int hb = h * 32;

        s16x8 qf0 = {}, qf1 = {};
        int i = i0 + c;
        if (i < NGLO) {
            const u16* qp = gqb + ((size_t)i * 2) * 256 + hb + qd * 8;
            qf0 = *(const s16x8*)qp;
            qf1 = *(const s16x8*)(qp + 256);
        }
#pragma unroll
        for (int z = 0; z < 8; ++z) qf0[z] ^= (short)0x8000;

        f32x4 o0[2] = {}, t1[2] = {};

        for (int j0 = 0; j0 < NGLO; j0 += 32) {
            s16x8 kf[2][2], vf[2][2];
#pragma unroll
            for (int b = 0; b < 2; ++b)
#pragma unroll
                for (int js = 0; js < 2; ++js) {
                    int j = j0 + js * 16 + c;
                    s16x8 kv = {};
                    if (j < NGLO) kv = *(const s16x8*)(gkb + ((size_t)j * 2 + b) * 256 + hb + qd * 8);
                    kf[b][js] = kv;
                }
#pragma unroll
            for (int b = 0; b < 2; ++b)
#pragma unroll
                for (int dh = 0; dh < 2; ++dh)
                    vf[b][dh] = *(const s16x8*)(gvt + (size_t)(b * 256 + hb + dh * 16 + c) * 128
                                                + j0 + qd * 8);

            f32x4 z4 = {};
            f32x4 sd0 = __builtin_amdgcn_mfma_f32_16x16x32_bf16(qf0, kf[0][0], z4, 0, 0, 0);
            sd0       = __builtin_amdgcn_mfma_f32_16x16x32_bf16(qf1, kf[1][0], sd0, 0, 0, 0);
            f32x4 sd1 = __builtin_amdgcn_mfma_f32_16x16x32_bf16(qf0, kf[0][1], z4, 0, 0, 0);
            sd1       = __builtin_amdgcn_mfma_f32_16x16x32_bf16(qf1, kf[1][1], sd1, 0, 0, 0);
#pragma unroll
            for (int r = 0; r < 4; ++r) {
                float e0v = __expf(sd0[r] * 0.17677669529663687f);
                At4[w][4 * qd + r][c]      = f2bf(__builtin_amdgcn_rcpf(1.f + e0v));
                float e1v = __expf(sd1[r] * 0.17677669529663687f);
                At4[w][4 * qd + r][16 + c] = f2bf(__builtin_amdgcn_rcpf(1.f + e1v));
            }
            asm volatile("s_waitcnt lgkmcnt(0)" ::: "memory");
            s16x8 af = *(const s16x8*)&At4[w][c][qd * 8];
            o0[0] = __builtin_amdgcn_mfma_f32_16x16x32_bf16(af, vf[0][0], o0[0], 0, 0, 0);
            o0[1] = __builtin_amdgcn_mfma_f32_16x16x32_bf16(af, vf[0][1], o0[1], 0, 0, 0);
            t1[0] = __builtin_amdgcn_mfma_f32_16x16x32_bf16(af, vf[1][0], t1[0], 0, 0, 0);
            t1[1] = __builtin_amdgcn_mfma_f32_16x16x32_bf16(af, vf[1][1], t1[1], 0, 0, 0);
        }

#pragma unroll
        for (int dh = 0; dh < 2; ++dh) {
            float sv = sv1g[hb + dh * 16 + c];
#pragma unroll
            for (int r = 0; r < 4; ++r) {
                int ii = i0 + 4 * qd + r;
                if (ii < NGLO) {
                    size_t o = ((size_t)ii * 2) * 256 + hb + dh * 16 + c;
                    gattb[o]       = (u16)f2bf(o0[dh][r]);
                    gattb[o + 256] = (u16)f2bf(sv - t1[dh][r]);
                }
            }
        }
    }
}

// ===========================================================================
// K5: combine (bx<400) + global proj+LN fused (bx>=400, 13 wave tasks).
// ===========================================================================
__global__ __launch_bounds__(256) void k_combine_gproj(
    const float* __restrict__ pO, const float* __restrict__ pT,
    const float* __restrict__ sv1l, u16* __restrict__ attb,
    const u16* __restrict__ gattb, const u16* __restrict__ W0p,
    const float* __restrict__ b0p, const float* __restrict__ gn,
    const float* __restrict__ ln_g, const float* __restrict__ ln_b,
    float* __restrict__ gout, u16* __restrict__ goutb)
{
    int bx = blockIdx.x;
    if (bx < 400) {
        int t4 = (bx * 256 + threadIdx.x) * 4;     // 0..409596 step 4
        int e = t4 & 255;
        int i = t4 >> 8;
        float4 o  = *(const float4*)(pO + t4);
        float4 tt = *(const float4*)(pT + t4);
#pragma unroll
        for (int q = 1; q < 4; ++q) {
            float4 a = *(const float4*)(pO + t4 + q * 409600);
            float4 b = *(const float4*)(pT + t4 + q * 409600);
            o.x += a.x; o.y += a.y; o.z += a.z; o.w += a.w;
            tt.x += b.x; tt.y += b.y; tt.z += b.z; tt.w += b.w;
        }
        float4 sv = *(const float4*)(sv1l + e);
        ushort4 w0, w1;
        w0.x = (u16)f2bf(o.x); w0.y = (u16)f2bf(o.y);
        w0.z = (u16)f2bf(o.z); w0.w = (u16)f2bf(o.w);
        w1.x = (u16)f2bf(sv.x - tt.x); w1.y = (u16)f2bf(sv.y - tt.y);
        w1.z = (u16)f2bf(sv.z - tt.z); w1.w = (u16)f2bf(sv.w - tt.w);
        *(ushort4*)(attb + (size_t)i * 512 + e)       = w0;
        *(ushort4*)(attb + (size_t)i * 512 + 256 + e) = w1;
    } else {
        int w = threadIdx.x >> 6, lane = threadIdx.x & 63;
        int idx = (bx - 400) * 4 + w;
        if (idx < 13)
            gemmln_wave(lane, gattb, W0p, b0p, gn, ln_g, ln_b,
                        gout, goutb, (float*)0, 200, idx * 16, 0);
    }
}

// ===========================================================================
// K6: local proj+LN fused (bx<50, 200 wave tasks) + ck/cv GEMM (bx>=50, 56 tasks)
// ===========================================================================
__global__ __launch_bounds__(256) void k_lproj_ckcv(
    const u16* __restrict__ attb, const u16* __restrict__ W1p,
    const float* __restrict__ b1p, const float* __restrict__ nodes,
    const float* __restrict__ ln_g1, const float* __restrict__ ln_b1,
    float* __restrict__ lout, u16* __restrict__ loutb,
    const u16* __restrict__ goutb, const u16* __restrict__ wckv,
    const float* __restrict__ bckv, u16* __restrict__ ckb)
{
    int bx = blockIdx.x;
    int w = threadIdx.x >> 6, lane = threadIdx.x & 63;
    if (bx < 50) {
        int idx = bx * 4 + w;                          // 0..199
        gemmln_wave(lane, attb, W1p, b1p, nodes, ln_g1, ln_b1,
                    lout, loutb, (float*)0, 3200, idx * 16, 0);
    } else {
        int idx = (bx - 50) * 4 + w;                   // 0..55
        int z = idx / 28, rem = idx % 28;
        int m0 = (rem >> 2) * 32, n0 = (rem & 3) * 64;
        gemm_tile(lane, goutb, wckv + (size_t)z * 65536, bckv + z * 256,
                  ckb + (size_t)z * 51200, 200, m0, n0);
    }
}

// ===========================================================================
// K7: cq GEMM (bx<100, 400 wave tasks) + cv transpose (bx>=100, 64 blocks)
// ===========================================================================
__global__ __launch_bounds__(256) void k_cq_vtrans(
    const u16* __restrict__ loutb, const u16* __restrict__ wcq,
    const float* __restrict__ bcq, u16* __restrict__ cqb,
    const u16* __restrict__ cvb, u16* __restrict__ cvt)
{
    int bx = blockIdx.x;
    if (bx < 100) {
        int w = threadIdx.x >> 6, lane = threadIdx.x & 63;
        int idx = bx * 4 + w;                          // 0..399
        int m0 = (idx % 100) * 32, n0 = (idx / 100) * 64;
        gemm_tile(lane, loutb, wcq, bcq, cqb, 3200, m0, n0);
    } else {
        int bb = bx - 100;
        __shared__ u16 tile[32][33];
        int m0 = (bb & 7) * 32;
        int e0 = (bb >> 3) * 32;
        int tx = threadIdx.x & 31, ty = threadIdx.x >> 5;
#pragma unroll
        for (int k2 = 0; k2 < 4; ++k2) {
            int m = m0 + ty + k2 * 8;
            tile[ty + k2 * 8][tx] = (m < 200) ? cvb[(size_t)m * 256 + e0 + tx] : (u16)0;
        }
        __syncthreads();
        int b = tx >> 4, nl = tx & 15;
        int n = (m0 >> 1) + nl;
#pragma unroll
        for (int k2 = 0; k2 < 4; ++k2) {
            int e = e0 + ty + k2 * 8;
            cvt[(size_t)(b * 256 + e) * 128 + n] = tile[2 * nl + b][ty + k2 * 8];
        }
    }
}

// ===========================================================================
// K8: cross attention, 4 waves/block, 1600 wave tasks (400 blocks).
// Softmax over 100 pooled keys (x16 upsample multiplicity cancels).
// ===========================================================================
__global__ __launch_bounds__(256) void k_cross(
    const u16* __restrict__ qb, const u16* __restrict__ kb,
    const u16* __restrict__ vt, u16* __restrict__ out)
{
    __shared__ short At[4][16][136];
    int w = threadIdx.x >> 6, lane = threadIdx.x & 63;
    int c  = lane & 15;
    int qd = lane >> 4;
    int idx = blockIdx.x * 4 + w;
    int it = idx % 100;
    int hb2 = idx / 100;
    int h = hb2 >> 1, b = hb2 & 1;
    int i0 = it * 16;
    int hb = h * 32;

    for (int z = lane; z < 16 * 24; z += 64)
        At[w][z / 24][112 + (z % 24)] = 0;

    const u16* qp = qb + ((size_t)(i0 + c) * 2 + b) * 256 + hb + qd * 8;
    s16x8 qf = *(const s16x8*)qp;

    f32x4 s[7];
#pragma unroll
    for (int jt = 0; jt < 7; ++jt) {
        int j = jt * 16 + c;
        s16x8 kf = {};
        if (j < NGLO) kf = *(const s16x8*)(kb + ((size_t)j * 2 + b) * 256 + hb + qd * 8);
        f32x4 z4 = {};
        s[jt] = __builtin_amdgcn_mfma_f32_16x16x32_bf16(qf, kf, z4, 0, 0, 0);
    }
    if (c >= 4) {
#pragma unroll
        for (int r = 0; r < 4; ++r) s[6][r] = -1e30f;
    }
#pragma unroll
    for (int jt = 0; jt < 7; ++jt)
#pragma unroll
        for (int r = 0; r < 4; ++r) s[jt][r] *= 0.17677669529663687f;

    float l[4];
#pragma unroll
    for (int r = 0; r < 4; ++r) {
        float mm = s[0][r];
#pragma unroll
        for (int jt = 1; jt < 7; ++jt) mm = fmaxf(mm, s[jt][r]);
        mm = fmaxf(mm, __shfl_xor(mm, 1));
        mm = fmaxf(mm, __shfl_xor(mm, 2));
        mm = fmaxf(mm, __shfl_xor(mm, 4));
        mm = fmaxf(mm, __shfl_xor(mm, 8));
        float ll = 0.f;
#pragma unroll
        for (int jt = 0; jt < 7; ++jt) {
            float p = __expf(s[jt][r] - mm);
            s[jt][r] = p;
            ll += p;
        }
        ll += __shfl_xor(ll, 1);
        ll += __shfl_xor(ll, 2);
        ll += __shfl_xor(ll, 4);
        ll += __shfl_xor(ll, 8);
        l[r] = ll;
    }
#pragma unroll
    for (int jt = 0; jt < 7; ++jt)
#pragma unroll
        for (int r = 0; r < 4; ++r)
            At[w][4 * qd + r][jt * 16 + c] = f2bf(s[jt][r]);
    asm volatile("s_waitcnt lgkmcnt(0)" ::: "memory");

    f32x4 o[2] = {};
#pragma unroll
    for (int kc = 0; kc < 4; ++kc) {
        s16x8 af = *(const s16x8*)&At[w][c][kc * 32 + qd * 8];
#pragma unroll
        for (int dh = 0; dh < 2; ++dh) {
            s16x8 vf = *(const s16x8*)(vt + (size_t)(b * 256 + hb + dh * 16 + c) * 128
                                       + kc * 32 + qd * 8);
            o[dh] = __builtin_amdgcn_mfma_f32_16x16x32_bf16(af, vf, o[dh], 0, 0, 0);
        }
    }
#pragma unroll
    for (int dh = 0; dh < 2; ++dh)
#pragma unroll
        for (int r = 0; r < 4; ++r) {
            int ii = i0 + 4 * qd + r;
            out[((size_t)ii * 2 + b) * 256 + hb + dh * 16 + c] = (u16)f2bf(o[dh][r] / l[r]);
        }
}

// ===========================================================================
// K9: final cproj + LN fused, writes BCHW output. 50 blocks, 200 wave tasks.
// ===========================================================================
__global__ __launch_bounds__(256) void k_cproj(
    const u16* __restrict__ cattb, const u16* __restrict__ wcp,
    const float* __restrict__ bcp, const float* __restrict__ lout,
    const float* __restrict__ ln_g2, const float* __restrict__ ln_b2,
    float* __restrict__ dout)
{
    int w = threadIdx.x >> 6, lane = threadIdx.x & 63;
    int idx = blockIdx.x * 4 + w;                      // 0..199
    gemmln_wave(lane, cattb, wcp, bcp, lout, ln_g2, ln_b2,
                (float*)0, (u16*)0, dout, 3200, idx * 16, 1);
}

// ===========================================================================
extern "C" void kernel_launch(void* const* d_in, const int* in_sizes, int n_in,
                              void* d_out, int out_size, void* d_ws, size_t ws_size,
                              hipStream_t stream) {
    const float* x        = (const float*)d_in[0];
    const float* gat_W    = (const float*)d_in[1];  // [2][4][256][256]
    const float* gat_b    = (const float*)d_in[2];  // [2][4][256]
    // d_in[3] = gat_rel: cancels in the batch-axis softmax -> unused
    const float* cross_W  = (const float*)d_in[4];  // [4][256][256]
    const float* cross_b  = (const float*)d_in[5];  // [4][256]
    const float* ln_g     = (const float*)d_in[6];  // [3][256]
    const float* ln_b     = (const float*)d_in[7];  // [3][256]
    float* out = (float*)d_out;

    float* ws    = (float*)d_ws;
    float* nodes = ws;                      // [1600][2][256] f32
    float* lout  = nodes + 819200;          // local GAT output f32 (alias pO)
    float* proj  = lout  + 819200;          // (spare f32)
    float* gn    = proj  + 819200;          // [100][2][256] f32
    float* gprj  = gn    + 51200;           // (spare)
    float* gout  = gprj  + 51200;
    float* sv1l  = gout  + 51200;           // [256]
    float* sv1g  = sv1l  + 256;             // [256]
    float* pT    = sv1g  + 256;             // [4][1600][256] f32 partial T
    float* pO    = lout;                    // alias: lout dead during attn
    u16* wgatb  = (u16*)(pT + 1638400);     // 2*4*65536 bf16 weights
    u16* wcrsb  = wgatb + 524288;           // 4*65536
    u16* nodesb = wcrsb + 262144;           // [1600][2][256] bf16
    u16* qbuf   = nodesb + 819200;          // q/k/v contiguous (z-batched)
    u16* kbuf   = qbuf + 819200;            // later reused as cattb
    u16* vbuf   = kbuf + 819200;            // later reused as loutb
    u16* vtb    = vbuf + 819200;            // [2][256][1600]
    u16* attb   = vtb + 819200;             // l_att; later reused as cqb
    u16* gnb    = attb + 819200;            // [100][2][256]
    u16* gqb    = gnb + 51200;              // gqb/gkb/gvb contiguous
    u16* gkb    = gqb + 51200;
    u16* gvb    = gkb + 51200;
    u16* gvt    = gvb + 51200;              // [2][256][128]
    u16* gattb  = gvt + 65536;
    u16* goutb  = gattb + 51200;
    u16* ckb    = goutb + 51200;            // ckb/cvb contiguous
    u16* cvb    = ckb + 51200;
    u16* cvt    = cvb + 51200;              // [2][256][128]
    u16* loutb  = vbuf;                     // reuse (V consumed by K3)
    u16* cqb    = attb;                     // reuse (attb consumed by K6)
    u16* cattb  = kbuf;                     // reuse (kbuf consumed by K4)

    const u16* W0b = wgatb;                 // global GAT weights bf16
    const u16* W1b = wgatb + 4 * 65536;     // local GAT weights bf16
    const float* b0 = gat_b;
    const float* b1 = gat_b + 4 * 256;

    k_prep<<<4168, 256, 0, stream>>>(gat_W, cross_W, wgatb, wcrsb,
                                     x, nodes, nodesb, gn, gnb);
    k_qkv<<<dim3(107, 4, 3), 64, 0, stream>>>(nodesb, gnb, W1b, W0b, b1, b0,
                                              qbuf, gqb, sv1l);
    k_vtrans<<<dim3(108, 8), 256, 0, stream>>>(vbuf, vtb, gvb, gvt, sv1l, sv1g);
    k_attn<<<814, 256, 0, stream>>>(qbuf, kbuf, vtb, pO, pT,
                                    gqb, gkb, gvt, sv1g, gattb);
    k_combine_gproj<<<404, 256, 0, stream>>>(pO, pT, sv1l, attb,
                                             gattb, W0b + 3 * 65536, b0 + 768, gn,
                                             ln_g, ln_b, gout, goutb);
    k_lproj_ckcv<<<64, 256, 0, stream>>>(attb, W1b + 3 * 65536, b1 + 768, nodes,
                                         ln_g + 256, ln_b + 256, lout, loutb,
                                         goutb, wcrsb + 65536, cross_b + 256, ckb);
    k_cq_vtrans<<<164, 256, 0, stream>>>(loutb, wcrsb, cross_b, cqb, cvb, cvt);
    k_cross<<<400, 256, 0, stream>>>(cqb, ckb, cvt, cattb);
    k_cproj<<<50, 256, 0, stream>>>(cattb, wcrsb + 3 * 65536, cross_b + 768, lout,
                                    ln_g + 512, ln_b + 512, out);
}

// Round 6
// 166.972 us; speedup vs baseline: 1.4669x; 1.4669x over previous
//
#include <hip/hip_runtime.h>
#include <math.h>

#define NLOC 1600          // 40*40 local nodes
#define NGLO 100           // 10*10 global nodes

typedef unsigned short u16;
typedef short s16x8 __attribute__((ext_vector_type(8)));   // 8 bf16 (4 VGPRs)
typedef float f32x4 __attribute__((ext_vector_type(4)));   // MFMA C/D

__device__ __forceinline__ short f2bf(float f) {           // RNE f32->bf16
    unsigned u = __float_as_uint(f);
    u += 0x7fffu + ((u >> 16) & 1u);
    return (short)(u >> 16);
}
__device__ __forceinline__ float bf2f(u16 h) {
    return __uint_as_float(((unsigned)h) << 16);
}

// ===========================================================================
// Device helpers
// ===========================================================================

// Plain MFMA GEMM tile: C[m0..m0+32][n0..n0+64] = A[M,256] @ W^T + bias, bf16 out.
__device__ __forceinline__ void gemm_tile(int lane, const u16* __restrict__ A,
                                          const u16* __restrict__ W,
                                          const float* __restrict__ bias,
                                          u16* __restrict__ C, int M, int m0, int n0) {
    int c = lane & 15, qd = lane >> 4;
    f32x4 acc[2][4] = {};
#pragma unroll 2
    for (int kc = 0; kc < 8; ++kc) {
        int ko = kc * 32 + qd * 8;
        s16x8 af[2], bf[4];
#pragma unroll
        for (int mi = 0; mi < 2; ++mi) {
            int row = m0 + mi * 16 + c;
            s16x8 zz = {};
            af[mi] = (row < M) ? *(const s16x8*)(A + (size_t)row * 256 + ko) : zz;
        }
#pragma unroll
        for (int ni = 0; ni < 4; ++ni)
            bf[ni] = *(const s16x8*)(W + (size_t)(n0 + ni * 16 + c) * 256 + ko);
#pragma unroll
        for (int mi = 0; mi < 2; ++mi)
#pragma unroll
            for (int ni = 0; ni < 4; ++ni)
                acc[mi][ni] = __builtin_amdgcn_mfma_f32_16x16x32_bf16(af[mi], bf[ni],
                                                                      acc[mi][ni], 0, 0, 0);
    }
#pragma unroll
    for (int mi = 0; mi < 2; ++mi)
#pragma unroll
        for (int r = 0; r < 4; ++r) {
            int row = m0 + mi * 16 + 4 * qd + r;
            if (row < M) {
#pragma unroll
                for (int ni = 0; ni < 4; ++ni) {
                    int col = n0 + ni * 16 + c;
                    C[(size_t)row * 256 + col] = (u16)f2bf(acc[mi][ni][r] + bias[col]);
                }
            }
        }
}

// Fused GEMM + LayerNorm, 4-wave block: 16 rows x 256 cols per BLOCK.
// Wave w computes cols w*64..w*64+63; LN stats reduced across waves via LDS.
// y = LN(A@W^T + bias + R) * g + bb.
// MODE 0: fout[row][col] f32 + bfout bf16 shadow.
// MODE 1: dout[(b*256+col)*1600 + row/2] (final BCHW write), row = n*2+b,
//         staged through LDS for 32B-contiguous global stores.
template <int MODE>
__device__ __forceinline__ void gemmln_block(int tid, const u16* __restrict__ A,
                                             const u16* __restrict__ W,
                                             const float* __restrict__ bias,
                                             const float* __restrict__ R,
                                             const float* __restrict__ g,
                                             const float* __restrict__ bb,
                                             float* fout, u16* bfout, float* dout,
                                             int M, int m0) {
    int w = tid >> 6, lane = tid & 63;
    int c = lane & 15, qd = lane >> 4;
    int n0 = w * 64;

    f32x4 acc[4] = {};
#pragma unroll 2
    for (int kc = 0; kc < 8; ++kc) {
        int ko = kc * 32 + qd * 8;
        int row = m0 + c;
        s16x8 zz = {};
        s16x8 af = (row < M) ? *(const s16x8*)(A + (size_t)row * 256 + ko) : zz;
#pragma unroll
        for (int ni = 0; ni < 4; ++ni) {
            s16x8 bf = *(const s16x8*)(W + (size_t)(n0 + ni * 16 + c) * 256 + ko);
            acc[ni] = __builtin_amdgcn_mfma_f32_16x16x32_bf16(af, bf, acc[ni], 0, 0, 0);
        }
    }

    __shared__ float ps1[4][16], ps2[4][16];
    float v[4][4];   // [r][ni]
#pragma unroll
    for (int r = 0; r < 4; ++r) {
        int row = m0 + 4 * qd + r;
        bool ok = (row < M);
        float s1 = 0.f, s2 = 0.f;
#pragma unroll
        for (int ni = 0; ni < 4; ++ni) {
            int col = n0 + ni * 16 + c;
            float val = acc[ni][r] + bias[col] + (ok ? R[(size_t)row * 256 + col] : 0.f);
            v[r][ni] = val;
            s1 += val; s2 += val * val;
        }
        s1 += __shfl_xor(s1, 1); s2 += __shfl_xor(s2, 1);
        s1 += __shfl_xor(s1, 2); s2 += __shfl_xor(s2, 2);
        s1 += __shfl_xor(s1, 4); s2 += __shfl_xor(s2, 4);
        s1 += __shfl_xor(s1, 8); s2 += __shfl_xor(s2, 8);
        if (c == 0) { ps1[w][4 * qd + r] = s1; ps2[w][4 * qd + r] = s2; }
    }
    __syncthreads();

    if (MODE == 0) {
#pragma unroll
        for (int r = 0; r < 4; ++r) {
            int lr = 4 * qd + r;
            int row = m0 + lr;
            if (row >= M) continue;
            float s1 = ps1[0][lr] + ps1[1][lr] + ps1[2][lr] + ps1[3][lr];
            float s2 = ps2[0][lr] + ps2[1][lr] + ps2[2][lr] + ps2[3][lr];
            float mean = s1 * (1.f / 256.f);
            float var  = s2 * (1.f / 256.f) - mean * mean;
            float rstd = rsqrtf(var + 1e-5f);
#pragma unroll
            for (int ni = 0; ni < 4; ++ni) {
                int col = n0 + ni * 16 + c;
                float y = (v[r][ni] - mean) * rstd * g[col] + bb[col];
                fout[(size_t)row * 256 + col] = y;
                bfout[(size_t)row * 256 + col] = (u16)f2bf(y);
            }
        }
    } else {
        __shared__ float ytile[2][8][256];   // [b][n_loc][col]
#pragma unroll
        for (int r = 0; r < 4; ++r) {
            int lr = 4 * qd + r;             // row m0+lr, M=3200 exact (no check)
            float s1 = ps1[0][lr] + ps1[1][lr] + ps1[2][lr] + ps1[3][lr];
            float s2 = ps2[0][lr] + ps2[1][lr] + ps2[2][lr] + ps2[3][lr];
            float mean = s1 * (1.f / 256.f);
            float var  = s2 * (1.f / 256.f) - mean * mean;
            float rstd = rsqrtf(var + 1e-5f);
#pragma unroll
            for (int ni = 0; ni < 4; ++ni) {
                int col = n0 + ni * 16 + c;
                ytile[lr & 1][lr >> 1][col] = (v[r][ni] - mean) * rstd * g[col] + bb[col];
            }
        }
        __syncthreads();
        // 512 (b,col) chunks of 8 consecutive n -> 32B contiguous stores
#pragma unroll
        for (int p = tid; p < 512; p += 256) {
            int b = p >> 8, col = p & 255;
            float4 y0, y1;
            y0.x = ytile[b][0][col]; y0.y = ytile[b][1][col];
            y0.z = ytile[b][2][col]; y0.w = ytile[b][3][col];
            y1.x = ytile[b][4][col]; y1.y = ytile[b][5][col];
            y1.z = ytile[b][6][col]; y1.w = ytile[b][7][col];
            size_t o = ((size_t)(b * 256 + col)) * 1600 + (m0 >> 1);
            *(float4*)(dout + o)     = y0;
            *(float4*)(dout + o + 4) = y1;
        }
    }
}

// ===========================================================================
// K1: wconv (768 blocks) + prep transpose/pool (3400 blocks)
// ===========================================================================
__global__ __launch_bounds__(256) void k_prep(const float* __restrict__ gw,
                                              const float* __restrict__ cw,
                                              u16* __restrict__ gwb,
                                              u16* __restrict__ cwb,
                                              const float* __restrict__ x,
                                              float* __restrict__ nodes,
                                              u16* __restrict__ nodesb,
                                              float* __restrict__ gn,
                                              u16* __restrict__ gnb) {
    int bx = blockIdx.x;
    if (bx < 768) {
        int t = bx * 256 + threadIdx.x;    // 0..196607
        const float* src; u16* dst; int idx;
        if (t < 131072) { src = gw; dst = gwb; idx = t; }
        else            { src = cw; dst = cwb; idx = t - 131072; }
        float4 v = ((const float4*)src)[idx];
        ushort4 o;
        o.x = (u16)f2bf(v.x); o.y = (u16)f2bf(v.y);
        o.z = (u16)f2bf(v.z); o.w = (u16)f2bf(v.w);
        ((ushort4*)dst)[idx] = o;
        return;
    }
    int bid = bx - 768;
    if (bid < 3200) {
        int t = bid * 256 + threadIdx.x;
        int c = t & 255;
        int b = (t >> 8) & 1;
        int n = t >> 9;
        float v = x[((size_t)(b * 256 + c)) * 1600 + n];
        nodes[t] = v;
        nodesb[t] = (u16)f2bf(v);
    } else {
        int t = (bid - 3200) * 256 + threadIdx.x;
        int c = t & 255;
        int b = (t >> 8) & 1;
        int n = t >> 9;
        int p = n / 10, qq = n - p * 10;
        const float* xp = x + ((size_t)(b * 256 + c)) * 1600 + (p * 4) * 40 + qq * 4;
        float s = 0.f;
#pragma unroll
        for (int dy = 0; dy < 4; ++dy)
#pragma unroll
            for (int dx = 0; dx < 4; ++dx)
                s += xp[dy * 40 + dx];
        s *= (1.f / 16.f);
        gn[t] = s;
        gnb[t] = (u16)f2bf(s);
    }
}

// ===========================================================================
// K2: QKV GEMMs, local (bx<100) + global (bx>=100). grid (107, 4, 3), 64 thr.
// Also zero-inits sv1l/sv1g (512 contiguous floats) from block (100,0,0).
// ===========================================================================
__global__ __launch_bounds__(64) void k_qkv(const u16* __restrict__ nodesb,
                                            const u16* __restrict__ gnb,
                                            const u16* __restrict__ W1b,
                                            const u16* __restrict__ W0b,
                                            const float* __restrict__ b1,
                                            const float* __restrict__ b0,
                                            u16* __restrict__ qbuf,
                                            u16* __restrict__ gqb,
                                            float* __restrict__ sv1) {
    int lane = threadIdx.x;
    int bx = blockIdx.x, z = blockIdx.z;
    int n0 = blockIdx.y * 64;
    if (bx == 100 && blockIdx.y == 0 && z == 0) {
#pragma unroll
        for (int i = 0; i < 8; ++i) sv1[lane * 8 + i] = 0.f;
    }
    if (bx < 100)
        gemm_tile(lane, nodesb, W1b + (size_t)z * 65536, b1 + z * 256,
                  qbuf + (size_t)z * 819200, 3200, bx * 32, n0);
    else
        gemm_tile(lane, gnb, W0b + (size_t)z * 65536, b0 + z * 256,
                  gqb + (size_t)z * 51200, 200, (bx - 100) * 32, n0);
}

// ===========================================================================
// K3: V transpose + fused colsum (batch-1) atomics.
// grid (108, 8): bx<100 local (vbuf->vtb, M=3200, Npad=1600, sv1l),
//                bx>=100 global (gvb->gvt, M=200, Npad=128, sv1g).
// ===========================================================================
__device__ __forceinline__ void vtrans_block(const u16* __restrict__ src,
                                             u16* __restrict__ dst,
                                             int M, int Npad, int bxx, int byy,
                                             float* sum) {
    __shared__ u16 tile[32][33];
    int m0 = bxx * 32;
    int e0 = byy * 32;
    int tx = threadIdx.x & 31, ty = threadIdx.x >> 5;
#pragma unroll
    for (int k2 = 0; k2 < 4; ++k2) {
        int m = m0 + ty + k2 * 8;
        tile[ty + k2 * 8][tx] = (m < M) ? src[(size_t)m * 256 + e0 + tx] : (u16)0;
    }
    __syncthreads();
    int b = tx >> 4, nl = tx & 15;
    int n = (m0 >> 1) + nl;
    if (n < Npad) {
#pragma unroll
        for (int k2 = 0; k2 < 4; ++k2) {
            int e = e0 + ty + k2 * 8;
            dst[(size_t)(b * 256 + e) * Npad + n] = tile[2 * nl + b][ty + k2 * 8];
        }
    }
    if (threadIdx.x < 32) {
        float s = 0.f;
#pragma unroll
        for (int r = 0; r < 16; ++r) s += bf2f(tile[2 * r + 1][threadIdx.x]);
        atomicAdd(&sum[e0 + threadIdx.x], s);
    }
}

__global__ __launch_bounds__(256) void k_vtrans(const u16* __restrict__ vbuf,
                                                u16* __restrict__ vtb,
                                                const u16* __restrict__ gvb,
                                                u16* __restrict__ gvt,
                                                float* __restrict__ sv1l,
                                                float* __restrict__ sv1g) {
    int bx = blockIdx.x;
    if (bx < 100) vtrans_block(vbuf, vtb, 3200, 1600, bx, blockIdx.y, sv1l);
    else          vtrans_block(gvb, gvt, 200, 128, bx - 100, blockIdx.y, sv1g);
}

// ===========================================================================
// K4: attention. blocks 0..799: local GAT (4-wave, LDS-staged, j-quarters);
// blocks 800..813: global GAT (wave-per-(h,it), 56 wave tasks).
// a0 = sigmoid((q1k1-q0k0)/sqrt32); edge bias cancels; O1 = sumV1 - sum a0*V1.
// ===========================================================================
__global__ __launch_bounds__(256) void k_attn(
    const u16* __restrict__ qb, const u16* __restrict__ kb,
    const u16* __restrict__ vt, float* __restrict__ pO, float* __restrict__ pT,
    const u16* __restrict__ gqb, const u16* __restrict__ gkb,
    const u16* __restrict__ gvt, const float* __restrict__ sv1g,
    u16* __restrict__ gattb)
{
    __shared__ u16 ks[2][32][40];
    __shared__ u16 vs[2][32][40];
    __shared__ short At4[4][16][40];

    int tid = threadIdx.x;
    int w = tid >> 6, lane = tid & 63;
    int c = lane & 15, qd = lane >> 4;
    int bx = blockIdx.x;

    if (bx < 800) {
        // ---------------- local ----------------
        int q4 = bx & 3;
        int hic = bx >> 2;
        int ic = hic % 25, h = hic / 25;
        int hb = h * 32;
        int i0 = ic * 64 + w * 16;
        int jb0 = q4 * 13, jbe = (jb0 + 13 < 50) ? jb0 + 13 : 50;

        const u16* qp = qb + ((size_t)(i0 + c) * 2) * 256 + hb + qd * 8;
        s16x8 qf0 = *(const s16x8*)qp;
        s16x8 qf1 = *(const s16x8*)(qp + 256);
#pragma unroll
        for (int z = 0; z < 8; ++z) qf0[z] ^= (short)0x8000;

        f32x4 o0[2] = {}, t1[2] = {};

        int srow = tid >> 2, part = tid & 3;
        int sjl = srow >> 1, sb = srow & 1;
        int vb_ = srow >> 5, vd = srow & 31;

        for (int jb = jb0; jb < jbe; ++jb) {
            int j0 = jb * 32;
            __syncthreads();
            {
                s16x8 kv = *(const s16x8*)(kb + (size_t)(j0 + sjl) * 512 + sb * 256 + hb + part * 8);
                *(s16x8*)&ks[sb][sjl][part * 8] = kv;
                s16x8 vv = *(const s16x8*)(vt + (size_t)(vb_ * 256 + hb + vd) * 1600 + j0 + part * 8);
                *(s16x8*)&vs[vb_][vd][part * 8] = vv;
            }
            __syncthreads();

            s16x8 kf00 = *(const s16x8*)&ks[0][c][qd * 8];
            s16x8 kf10 = *(const s16x8*)&ks[1][c][qd * 8];
            s16x8 kf01 = *(const s16x8*)&ks[0][16 + c][qd * 8];
            s16x8 kf11 = *(const s16x8*)&ks[1][16 + c][qd * 8];

            f32x4 z4 = {};
            f32x4 sd0 = __builtin_amdgcn_mfma_f32_16x16x32_bf16(qf0, kf00, z4, 0, 0, 0);
            sd0       = __builtin_amdgcn_mfma_f32_16x16x32_bf16(qf1, kf10, sd0, 0, 0, 0);
            f32x4 sd1 = __builtin_amdgcn_mfma_f32_16x16x32_bf16(qf0, kf01, z4, 0, 0, 0);
            sd1       = __builtin_amdgcn_mfma_f32_16x16x32_bf16(qf1, kf11, sd1, 0, 0, 0);
#pragma unroll
            for (int r = 0; r < 4; ++r) {
                float e0v = __expf(sd0[r] * 0.17677669529663687f);
                At4[w][4 * qd + r][c]      = f2bf(__builtin_amdgcn_rcpf(1.f + e0v));
                float e1v = __expf(sd1[r] * 0.17677669529663687f);
                At4[w][4 * qd + r][16 + c] = f2bf(__builtin_amdgcn_rcpf(1.f + e1v));
            }
            asm volatile("s_waitcnt lgkmcnt(0)" ::: "memory");
            s16x8 af = *(const s16x8*)&At4[w][c][qd * 8];

            s16x8 vf00 = *(const s16x8*)&vs[0][c][qd * 8];
            s16x8 vf01 = *(const s16x8*)&vs[0][16 + c][qd * 8];
            s16x8 vf10 = *(const s16x8*)&vs[1][c][qd * 8];
            s16x8 vf11 = *(const s16x8*)&vs[1][16 + c][qd * 8];

            o0[0] = __builtin_amdgcn_mfma_f32_16x16x32_bf16(af, vf00, o0[0], 0, 0, 0);
            o0[1] = __builtin_amdgcn_mfma_f32_16x16x32_bf16(af, vf01, o0[1], 0, 0, 0);
            t1[0] = __builtin_amdgcn_mfma_f32_16x16x32_bf16(af, vf10, t1[0], 0, 0, 0);
            t1[1] = __builtin_amdgcn_mfma_f32_16x16x32_bf16(af, vf11, t1[1], 0, 0, 0);
        }

        size_t base = (size_t)q4 * 409600;
#pragma unroll
        for (int dh = 0; dh < 2; ++dh)
#pragma unroll
            for (int r = 0; r < 4; ++r) {
                size_t idx = base + (size_t)(i0 + 4 * qd + r) * 256 + hb + dh * 16 + c;
                pO[idx] = o0[dh][r];
                pT[idx] = t1[dh][r];
            }
    } else {
        // ---------------- global (N=100, Npad=128) ----------------
        int idx = (bx - 800) * 4 + w;      // 0..55 exact
        int h = idx / 7, it = idx % 7;
        int i0 = it * 16;
        int hb = h * 32;

        s16x8 qf0 = {}, qf1 = {};
        int i = i0 + c;
        if (i < NGLO) {
            const u16* qp = gqb + ((size_t)i * 2) * 256 + hb + qd * 8;
            qf0 = *(const s16x8*)qp;
            qf1 = *(const s16x8*)(qp + 256);
        }
#pragma unroll
        for (int z = 0; z < 8; ++z) qf0[z] ^= (short)0x8000;

        f32x4 o0[2] = {}, t1[2] = {};

        for (int j0 = 0; j0 < NGLO; j0 += 32) {
            s16x8 kf[2][2], vf[2][2];
#pragma unroll
            for (int b = 0; b < 2; ++b)
#pragma unroll
                for (int js = 0; js < 2; ++js) {
                    int j = j0 + js * 16 + c;
                    s16x8 kv = {};
                    if (j < NGLO) kv = *(const s16x8*)(gkb + ((size_t)j * 2 + b) * 256 + hb + qd * 8);
                    kf[b][js] = kv;
                }
#pragma unroll
            for (int b = 0; b < 2; ++b)
#pragma unroll
                for (int dh = 0; dh < 2; ++dh)
                    vf[b][dh] = *(const s16x8*)(gvt + (size_t)(b * 256 + hb + dh * 16 + c) * 128
                                                + j0 + qd * 8);

            f32x4 z4 = {};
            f32x4 sd0 = __builtin_amdgcn_mfma_f32_16x16x32_bf16(qf0, kf[0][0], z4, 0, 0, 0);
            sd0       = __builtin_amdgcn_mfma_f32_16x16x32_bf16(qf1, kf[1][0], sd0, 0, 0, 0);
            f32x4 sd1 = __builtin_amdgcn_mfma_f32_16x16x32_bf16(qf0, kf[0][1], z4, 0, 0, 0);
            sd1       = __builtin_amdgcn_mfma_f32_16x16x32_bf16(qf1, kf[1][1], sd1, 0, 0, 0);
#pragma unroll
            for (int r = 0; r < 4; ++r) {
                float e0v = __expf(sd0[r] * 0.17677669529663687f);
                At4[w][4 * qd + r][c]      = f2bf(__builtin_amdgcn_rcpf(1.f + e0v));
                float e1v = __expf(sd1[r] * 0.17677669529663687f);
                At4[w][4 * qd + r][16 + c] = f2bf(__builtin_amdgcn_rcpf(1.f + e1v));
            }
            asm volatile("s_waitcnt lgkmcnt(0)" ::: "memory");
            s16x8 af = *(const s16x8*)&At4[w][c][qd * 8];
            o0[0] = __builtin_amdgcn_mfma_f32_16x16x32_bf16(af, vf[0][0], o0[0], 0, 0, 0);
            o0[1] = __builtin_amdgcn_mfma_f32_16x16x32_bf16(af, vf[0][1], o0[1], 0, 0, 0);
            t1[0] = __builtin_amdgcn_mfma_f32_16x16x32_bf16(af, vf[1][0], t1[0], 0, 0, 0);
            t1[1] = __builtin_amdgcn_mfma_f32_16x16x32_bf16(af, vf[1][1], t1[1], 0, 0, 0);
        }

#pragma unroll
        for (int dh = 0; dh < 2; ++dh) {
            float sv = sv1g[hb + dh * 16 + c];
#pragma unroll
            for (int r = 0; r < 4; ++r) {
                int ii = i0 + 4 * qd + r;
                if (ii < NGLO) {
                    size_t o = ((size_t)ii * 2) * 256 + hb + dh * 16 + c;
                    gattb[o]       = (u16)f2bf(o0[dh][r]);
                    gattb[o + 256] = (u16)f2bf(sv - t1[dh][r]);
                }
            }
        }
    }
}

// ===========================================================================
// K5: combine (bx<400) + global proj+LN fused (bx in [400,413), 4-wave blocks).
// ===========================================================================
__global__ __launch_bounds__(256) void k_combine_gproj(
    const float* __restrict__ pO, const float* __restrict__ pT,
    const float* __restrict__ sv1l, u16* __restrict__ attb,
    const u16* __restrict__ gattb, const u16* __restrict__ W0p,
    const float* __restrict__ b0p, const float* __restrict__ gn,
    const float* __restrict__ ln_g, const float* __restrict__ ln_b,
    float* __restrict__ gout, u16* __restrict__ goutb)
{
    int bx = blockIdx.x;
    if (bx < 400) {
        int t4 = (bx * 256 + threadIdx.x) * 4;     // 0..409596 step 4
        int e = t4 & 255;
        int i = t4 >> 8;
        float4 o  = *(const float4*)(pO + t4);
        float4 tt = *(const float4*)(pT + t4);
#pragma unroll
        for (int q = 1; q < 4; ++q) {
            float4 a = *(const float4*)(pO + t4 + q * 409600);
            float4 b = *(const float4*)(pT + t4 + q * 409600);
            o.x += a.x; o.y += a.y; o.z += a.z; o.w += a.w;
            tt.x += b.x; tt.y += b.y; tt.z += b.z; tt.w += b.w;
        }
        float4 sv = *(const float4*)(sv1l + e);
        ushort4 w0, w1;
        w0.x = (u16)f2bf(o.x); w0.y = (u16)f2bf(o.y);
        w0.z = (u16)f2bf(o.z); w0.w = (u16)f2bf(o.w);
        w1.x = (u16)f2bf(sv.x - tt.x); w1.y = (u16)f2bf(sv.y - tt.y);
        w1.z = (u16)f2bf(sv.z - tt.z); w1.w = (u16)f2bf(sv.w - tt.w);
        *(ushort4*)(attb + (size_t)i * 512 + e)       = w0;
        *(ushort4*)(attb + (size_t)i * 512 + 256 + e) = w1;
    } else {
        gemmln_block<0>(threadIdx.x, gattb, W0p, b0p, gn, ln_g, ln_b,
                        gout, goutb, (float*)0, 200, (bx - 400) * 16);
    }
}

// ===========================================================================
// K6: local proj+LN fused (bx<200, 4-wave blocks) + ck/cv GEMM (bx>=200).
// ===========================================================================
__global__ __launch_bounds__(256) void k_lproj_ckcv(
    const u16* __restrict__ attb, const u16* __restrict__ W1p,
    const float* __restrict__ b1p, const float* __restrict__ nodes,
    const float* __restrict__ ln_g1, const float* __restrict__ ln_b1,
    float* __restrict__ lout, u16* __restrict__ loutb,
    const u16* __restrict__ goutb, const u16* __restrict__ wckv,
    const float* __restrict__ bckv, u16* __restrict__ ckb)
{
    int bx = blockIdx.x;
    if (bx < 200) {
        gemmln_block<0>(threadIdx.x, attb, W1p, b1p, nodes, ln_g1, ln_b1,
                        lout, loutb, (float*)0, 3200, bx * 16);
    } else {
        int w = threadIdx.x >> 6, lane = threadIdx.x & 63;
        int idx = (bx - 200) * 4 + w;                  // 0..55
        int z = idx / 28, rem = idx % 28;
        int m0 = (rem >> 2) * 32, n0 = (rem & 3) * 64;
        gemm_tile(lane, goutb, wckv + (size_t)z * 65536, bckv + z * 256,
                  ckb + (size_t)z * 51200, 200, m0, n0);
    }
}

// ===========================================================================
// K7: cq GEMM (bx<100, 400 wave tasks) + cv transpose (bx>=100, 64 blocks)
// ===========================================================================
__global__ __launch_bounds__(256) void k_cq_vtrans(
    const u16* __restrict__ loutb, const u16* __restrict__ wcq,
    const float* __restrict__ bcq, u16* __restrict__ cqb,
    const u16* __restrict__ cvb, u16* __restrict__ cvt)
{
    int bx = blockIdx.x;
    if (bx < 100) {
        int w = threadIdx.x >> 6, lane = threadIdx.x & 63;
        int idx = bx * 4 + w;                          // 0..399
        int m0 = (idx % 100) * 32, n0 = (idx / 100) * 64;
        gemm_tile(lane, loutb, wcq, bcq, cqb, 3200, m0, n0);
    } else {
        int bb = bx - 100;
        __shared__ u16 tile[32][33];
        int m0 = (bb & 7) * 32;
        int e0 = (bb >> 3) * 32;
        int tx = threadIdx.x & 31, ty = threadIdx.x >> 5;
#pragma unroll
        for (int k2 = 0; k2 < 4; ++k2) {
            int m = m0 + ty + k2 * 8;
            tile[ty + k2 * 8][tx] = (m < 200) ? cvb[(size_t)m * 256 + e0 + tx] : (u16)0;
        }
        __syncthreads();
        int b = tx >> 4, nl = tx & 15;
        int n = (m0 >> 1) + nl;
#pragma unroll
        for (int k2 = 0; k2 < 4; ++k2) {
            int e = e0 + ty + k2 * 8;
            cvt[(size_t)(b * 256 + e) * 128 + n] = tile[2 * nl + b][ty + k2 * 8];
        }
    }
}

// ===========================================================================
// K8: cross attention, 4 waves/block, 1600 wave tasks (400 blocks).
// Softmax over 100 pooled keys (x16 upsample multiplicity cancels).
// ===========================================================================
__global__ __launch_bounds__(256) void k_cross(
    const u16* __restrict__ qb, const u16* __restrict__ kb,
    const u16* __restrict__ vt, u16* __restrict__ out)
{
    __shared__ short At[4][16][136];
    int w = threadIdx.x >> 6, lane = threadIdx.x & 63;
    int c  = lane & 15;
    int qd = lane >> 4;
    int idx = blockIdx.x * 4 + w;
    int it = idx % 100;
    int hb2 = idx / 100;
    int h = hb2 >> 1, b = hb2 & 1;
    int i0 = it * 16;
    int hb = h * 32;

    for (int z = lane; z < 16 * 24; z += 64)
        At[w][z / 24][112 + (z % 24)] = 0;

    const u16* qp = qb + ((size_t)(i0 + c) * 2 + b) * 256 + hb + qd * 8;
    s16x8 qf = *(const s16x8*)qp;

    f32x4 s[7];
#pragma unroll
    for (int jt = 0; jt < 7; ++jt) {
        int j = jt * 16 + c;
        s16x8 kf = {};
        if (j < NGLO) kf = *(const s16x8*)(kb + ((size_t)j * 2 + b) * 256 + hb + qd * 8);
        f32x4 z4 = {};
        s[jt] = __builtin_amdgcn_mfma_f32_16x16x32_bf16(qf, kf, z4, 0, 0, 0);
    }
    if (c >= 4) {
#pragma unroll
        for (int r = 0; r < 4; ++r) s[6][r] = -1e30f;
    }
#pragma unroll
    for (int jt = 0; jt < 7; ++jt)
#pragma unroll
        for (int r = 0; r < 4; ++r) s[jt][r] *= 0.17677669529663687f;

    float l[4];
#pragma unroll
    for (int r = 0; r < 4; ++r) {
        float mm = s[0][r];
#pragma unroll
        for (int jt = 1; jt < 7; ++jt) mm = fmaxf(mm, s[jt][r]);
        mm = fmaxf(mm, __shfl_xor(mm, 1));
        mm = fmaxf(mm, __shfl_xor(mm, 2));
        mm = fmaxf(mm, __shfl_xor(mm, 4));
        mm = fmaxf(mm, __shfl_xor(mm, 8));
        float ll = 0.f;
#pragma unroll
        for (int jt = 0; jt < 7; ++jt) {
            float p = __expf(s[jt][r] - mm);
            s[jt][r] = p;
            ll += p;
        }
        ll += __shfl_xor(ll, 1);
        ll += __shfl_xor(ll, 2);
        ll += __shfl_xor(ll, 4);
        ll += __shfl_xor(ll, 8);
        l[r] = ll;
    }
#pragma unroll
    for (int jt = 0; jt < 7; ++jt)
#pragma unroll
        for (int r = 0; r < 4; ++r)
            At[w][4 * qd + r][jt * 16 + c] = f2bf(s[jt][r]);
    asm volatile("s_waitcnt lgkmcnt(0)" ::: "memory");

    f32x4 o[2] = {};
#pragma unroll
    for (int kc = 0; kc < 4; ++kc) {
        s16x8 af = *(const s16x8*)&At[w][c][kc * 32 + qd * 8];
#pragma unroll
        for (int dh = 0; dh < 2; ++dh) {
            s16x8 vf = *(const s16x8*)(vt + (size_t)(b * 256 + hb + dh * 16 + c) * 128
                                       + kc * 32 + qd * 8);
            o[dh] = __builtin_amdgcn_mfma_f32_16x16x32_bf16(af, vf, o[dh], 0, 0, 0);
        }
    }
#pragma unroll
    for (int dh = 0; dh < 2; ++dh)
#pragma unroll
        for (int r = 0; r < 4; ++r) {
            int ii = i0 + 4 * qd + r;
            out[((size_t)ii * 2 + b) * 256 + hb + dh * 16 + c] = (u16)f2bf(o[dh][r] / l[r]);
        }
}

// ===========================================================================
// K9: final cproj + LN fused, writes BCHW output. 200 blocks, 4 waves each.
// ===========================================================================
__global__ __launch_bounds__(256) void k_cproj(
    const u16* __restrict__ cattb, const u16* __restrict__ wcp,
    const float* __restrict__ bcp, const float* __restrict__ lout,
    const float* __restrict__ ln_g2, const float* __restrict__ ln_b2,
    float* __restrict__ dout)
{
    gemmln_block<1>(threadIdx.x, cattb, wcp, bcp, lout, ln_g2, ln_b2,
                    (float*)0, (u16*)0, dout, 3200, blockIdx.x * 16);
}

// ===========================================================================
extern "C" void kernel_launch(void* const* d_in, const int* in_sizes, int n_in,
                              void* d_out, int out_size, void* d_ws, size_t ws_size,
                              hipStream_t stream) {
    const float* x        = (const float*)d_in[0];
    const float* gat_W    = (const float*)d_in[1];  // [2][4][256][256]
    const float* gat_b    = (const float*)d_in[2];  // [2][4][256]
    // d_in[3] = gat_rel: cancels in the batch-axis softmax -> unused
    const float* cross_W  = (const float*)d_in[4];  // [4][256][256]
    const float* cross_b  = (const float*)d_in[5];  // [4][256]
    const float* ln_g     = (const float*)d_in[6];  // [3][256]
    const float* ln_b     = (const float*)d_in[7];  // [3][256]
    float* out = (float*)d_out;

    float* ws    = (float*)d_ws;
    float* nodes = ws;                      // [1600][2][256] f32
    float* lout  = nodes + 819200;          // local GAT output f32 (alias pO)
    float* proj  = lout  + 819200;          // (spare f32)
    float* gn    = proj  + 819200;          // [100][2][256] f32
    float* gprj  = gn    + 51200;           // (spare)
    float* gout  = gprj  + 51200;
    float* sv1l  = gout  + 51200;           // [256]
    float* sv1g  = sv1l  + 256;             // [256]
    float* pT    = sv1g  + 256;             // [4][1600][256] f32 partial T
    float* pO    = lout;                    // alias: lout dead during attn
    u16* wgatb  = (u16*)(pT + 1638400);     // 2*4*65536 bf16 weights
    u16* wcrsb  = wgatb + 524288;           // 4*65536
    u16* nodesb = wcrsb + 262144;           // [1600][2][256] bf16
    u16* qbuf   = nodesb + 819200;          // q/k/v contiguous (z-batched)
    u16* kbuf   = qbuf + 819200;            // later reused as cattb
    u16* vbuf   = kbuf + 819200;            // later reused as loutb
    u16* vtb    = vbuf + 819200;            // [2][256][1600]
    u16* attb   = vtb + 819200;             // l_att; later reused as cqb
    u16* gnb    = attb + 819200;            // [100][2][256]
    u16* gqb    = gnb + 51200;              // gqb/gkb/gvb contiguous
    u16* gkb    = gqb + 51200;
    u16* gvb    = gkb + 51200;
    u16* gvt    = gvb + 51200;              // [2][256][128]
    u16* gattb  = gvt + 65536;
    u16* goutb  = gattb + 51200;
    u16* ckb    = goutb + 51200;            // ckb/cvb contiguous
    u16* cvb    = ckb + 51200;
    u16* cvt    = cvb + 51200;              // [2][256][128]
    u16* loutb  = vbuf;                     // reuse (V consumed by K3)
    u16* cqb    = attb;                     // reuse (attb consumed by K6)
    u16* cattb  = kbuf;                     // reuse (kbuf consumed by K4)

    const u16* W0b = wgatb;                 // global GAT weights bf16
    const u16* W1b = wgatb + 4 * 65536;     // local GAT weights bf16
    const float* b0 = gat_b;
    const float* b1 = gat_b + 4 * 256;

    k_prep<<<4168, 256, 0, stream>>>(gat_W, cross_W, wgatb, wcrsb,
                                     x, nodes, nodesb, gn, gnb);
    k_qkv<<<dim3(107, 4, 3), 64, 0, stream>>>(nodesb, gnb, W1b, W0b, b1, b0,
                                              qbuf, gqb, sv1l);
    k_vtrans<<<dim3(108, 8), 256, 0, stream>>>(vbuf, vtb, gvb, gvt, sv1l, sv1g);
    k_attn<<<814, 256, 0, stream>>>(qbuf, kbuf, vtb, pO, pT,
                                    gqb, gkb, gvt, sv1g, gattb);
    k_combine_gproj<<<413, 256, 0, stream>>>(pO, pT, sv1l, attb,
                                             gattb, W0b + 3 * 65536, b0 + 768, gn,
                                             ln_g, ln_b, gout, goutb);
    k_lproj_ckcv<<<214, 256, 0, stream>>>(attb, W1b + 3 * 65536, b1 + 768, nodes,
                                          ln_g + 256, ln_b + 256, lout, loutb,
                                          goutb, wcrsb + 65536, cross_b + 256, ckb);
    k_cq_vtrans<<<164, 256, 0, stream>>>(loutb, wcrsb, cross_b, cqb, cvb, cvt);
    k_cross<<<400, 256, 0, stream>>>(cqb, ckb, cvt, cattb);
    k_cproj<<<200, 256, 0, stream>>>(cattb, wcrsb + 3 * 65536, cross_b + 768, lout,
                                     ln_g + 512, ln_b + 512, out);
}